// Round 1
// baseline (12385.859 us; speedup 1.0000x reference)
//
#include <hip/hip_runtime.h>

#define TT 1024
#define BB 64
#define HH 32
#define G4 128   // 4*H

__device__ __forceinline__ float rl(float v, int lane) {
    return __int_as_float(__builtin_amdgcn_readlane(__float_as_int(v), lane));
}
__device__ __forceinline__ float fexp2(float x) { return __builtin_amdgcn_exp2f(x); }
__device__ __forceinline__ float frcp(float x)  { return __builtin_amdgcn_rcpf(x); }

// ---------------------------------------------------------------------------
// xp = x @ w_ih.T + b_ih + b_hh  for both directions.
// out layout: xp[dir][b][t][128]
// grid: 65536 blocks (dir:1b, b:6b, tpair:9b), block 256 = 128 g x 2 t
// ---------------------------------------------------------------------------
template <int D>
__global__ __launch_bounds__(256) void xp_kernel(
    const float* __restrict__ xin,          // [B][T][D]
    const float* __restrict__ wih_f, const float* __restrict__ bih_f, const float* __restrict__ bhh_f,
    const float* __restrict__ wih_r, const float* __restrict__ bih_r, const float* __restrict__ bhh_r,
    float* __restrict__ xp)
{
    int bid   = blockIdx.x;
    int tpair = bid & (TT / 2 - 1); bid >>= 9;
    int b     = bid & (BB - 1);     bid >>= 6;
    int dir   = bid;
    int g     = threadIdx.x & 127;
    int t     = tpair * 2 + (threadIdx.x >> 7);

    const float* wih  = dir ? wih_r : wih_f;
    float bias        = dir ? (bih_r[g] + bhh_r[g]) : (bih_f[g] + bhh_f[g]);
    const float* xrow = xin + ((size_t)b * TT + t) * D;
    const float* wrow = wih + (size_t)g * D;

    float acc = bias;
    if constexpr ((D & 3) == 0) {
        #pragma unroll
        for (int d = 0; d < D; d += 4) {
            float4 xv = *(const float4*)(xrow + d);
            float4 wv = *(const float4*)(wrow + d);
            acc = fmaf(xv.x, wv.x, acc);
            acc = fmaf(xv.y, wv.y, acc);
            acc = fmaf(xv.z, wv.z, acc);
            acc = fmaf(xv.w, wv.w, acc);
        }
    } else {
        #pragma unroll
        for (int d = 0; d < D; ++d) acc = fmaf(xrow[d], wrow[d], acc);
    }
    xp[(((size_t)dir * BB + b) * TT + t) * G4 + g] = acc;
}

// ---------------------------------------------------------------------------
// LSTM recurrence, one wave per (dir, b). Lane l owns gate rows l and l+64.
// h broadcast via v_readlane; f/o cross half-wave via shfl_xor 32.
// hout[b][t][dir*32 + j] for j<32.
// ---------------------------------------------------------------------------
__global__ __launch_bounds__(64) void lstm_rec(
    const float* __restrict__ xp,     // [2][B][T][128] (biases already included)
    const float* __restrict__ whh_f,  // [128][32]
    const float* __restrict__ whh_r,  // [128][32]
    float* __restrict__ hout)         // [B][T][64]
{
    const int l   = threadIdx.x;
    const int dir = blockIdx.x >> 6;
    const int b   = blockIdx.x & 63;
    const float* whh = dir ? whh_r : whh_f;

    float w0[32], w1[32];
    #pragma unroll
    for (int j = 0; j < 8; ++j) {
        float4 v0 = ((const float4*)whh)[l * 8 + j];
        w0[4*j+0] = v0.x; w0[4*j+1] = v0.y; w0[4*j+2] = v0.z; w0[4*j+3] = v0.w;
        float4 v1 = ((const float4*)whh)[(l + 64) * 8 + j];
        w1[4*j+0] = v1.x; w1[4*j+1] = v1.y; w1[4*j+2] = v1.z; w1[4*j+3] = v1.w;
    }

    const int t0 = dir ? (TT - 1) : 0;
    const ptrdiff_t xstep = dir ? -G4 : G4;
    const ptrdiff_t hstep = dir ? -64 : 64;
    const float* xptr = xp + (((size_t)dir * BB + b) * TT + t0) * G4;
    float* hptr = hout + ((size_t)b * TT + t0) * 64 + (dir ? HH : 0);

    const float LOG2E = 1.4426950408889634f;
    const float kmul = (l < HH) ? (-2.0f * LOG2E) : (-LOG2E);  // tanh vs sigmoid arg scale
    const float vA   = (l < HH) ? 2.0f : 1.0f;                 // 2*s-1 vs s
    const float vB   = (l < HH) ? -1.0f : 0.0f;

    float c = 0.f, hval = 0.f;
    float pre0 = xptr[l], pre1 = xptr[l + 64];

    for (int s = 0; s < TT; ++s) {
        const float* xnext = xptr + xstep;   // prefetch always lands inside xp buffer
        float q00 = pre0, q01 = 0.f, q02 = 0.f, q03 = 0.f;
        float q10 = pre1, q11 = 0.f, q12 = 0.f, q13 = 0.f;
        pre0 = xnext[l]; pre1 = xnext[l + 64];

        #pragma unroll
        for (int j = 0; j < 32; j += 4) {
            float h0 = rl(hval, j + 0), h1 = rl(hval, j + 1);
            float h2 = rl(hval, j + 2), h3 = rl(hval, j + 3);
            q00 = fmaf(h0, w0[j+0], q00); q10 = fmaf(h0, w1[j+0], q10);
            q01 = fmaf(h1, w0[j+1], q01); q11 = fmaf(h1, w1[j+1], q11);
            q02 = fmaf(h2, w0[j+2], q02); q12 = fmaf(h2, w1[j+2], q12);
            q03 = fmaf(h3, w0[j+3], q03); q13 = fmaf(h3, w1[j+3], q13);
        }
        float g0 = (q00 + q01) + (q02 + q03);   // row l:    i (l<32) / f (l>=32)
        float g1 = (q10 + q11) + (q12 + q13);   // row l+64: g (l<32) / o (l>=32)

        float s0 = frcp(1.0f + fexp2(-LOG2E * g0));   // sigmoid(g0): i or f
        float s1 = frcp(1.0f + fexp2(kmul * g1));     // sigmoid(g1) or sigmoid(2*g1)
        float v1 = fmaf(s1, vA, vB);                  // tanh(g1) (l<32) or sigmoid (l>=32)

        float ff = __shfl_xor(s0, 32);   // lanes<32: f-gate
        float oo = __shfl_xor(s1, 32);   // lanes<32: o-gate

        c = fmaf(ff, c, s0 * v1);        // c = f*c + i*g   (valid in lanes<32)
        float th = fmaf(frcp(1.0f + fexp2(-2.0f * LOG2E * c)), 2.0f, -1.0f);  // tanh(c)
        hval = oo * th;

        if (l < HH) hptr[l] = hval;
        hptr += hstep;
        xptr = xnext;
    }
}

// ---------------------------------------------------------------------------
// transpose h1 [64][65536] -> flatT [65536][64]
// ---------------------------------------------------------------------------
__global__ __launch_bounds__(256) void transpose64(
    const float* __restrict__ in, float* __restrict__ out)
{
    __shared__ float tile[64][65];
    int k0 = blockIdx.x * 64;
    int cc = threadIdx.x & 63;
    int r0 = threadIdx.x >> 6;
    #pragma unroll
    for (int i = 0; i < 16; ++i) {
        int b = r0 + i * 4;
        tile[b][cc] = in[(size_t)b * 65536 + k0 + cc];
    }
    __syncthreads();
    #pragma unroll
    for (int i = 0; i < 16; ++i) {
        int kr = r0 + i * 4;
        out[(size_t)(k0 + kr) * 64 + cc] = tile[cc][kr];
    }
}

// ---------------------------------------------------------------------------
// fc1 partial GEMM: partial[s][o][b] = sum_{k in chunk s} flatT[k][b]*w[o][k]
// wave = 32 outputs x 2048-k chunk, lanes = b. Weights via scalar loads.
// grid 512 = 16 ogQuad x 32 s ; 4 waves of a block share the same k-chunk (L1 reuse)
// ---------------------------------------------------------------------------
__global__ __launch_bounds__(256) void fc1_partial(
    const float* __restrict__ flatT, const float* __restrict__ w,
    float* __restrict__ partial)
{
    int lane = threadIdx.x & 63;
    int wv   = __builtin_amdgcn_readfirstlane(threadIdx.x >> 6);
    int s    = blockIdx.x & 31;
    int og   = (blockIdx.x >> 5) * 4 + wv;
    size_t o0 = (size_t)og * 32;
    size_t k0 = (size_t)s * 2048;

    const float* fp = flatT + k0 * 64 + lane;
    const float* wp = w + o0 * 65536 + k0;

    float acc[32];
    #pragma unroll
    for (int i = 0; i < 32; ++i) acc[i] = 0.f;

    for (int k = 0; k < 2048; k += 4) {
        float f0 = fp[(k + 0) * 64], f1 = fp[(k + 1) * 64];
        float f2 = fp[(k + 2) * 64], f3 = fp[(k + 3) * 64];
        #pragma unroll
        for (int o = 0; o < 32; ++o) {
            const float* wr = wp + (size_t)o * 65536 + k;   // wave-uniform -> s_load
            float a = acc[o];
            a = fmaf(f0, wr[0], a);
            a = fmaf(f1, wr[1], a);
            a = fmaf(f2, wr[2], a);
            a = fmaf(f3, wr[3], a);
            acc[o] = a;
        }
    }
    float* pp = partial + ((size_t)s * 2048 + o0) * 64 + lane;
    #pragma unroll
    for (int o = 0; o < 32; ++o) pp[(size_t)o * 64] = acc[o];
}

// ---------------------------------------------------------------------------
// reduce partials + bias + relu -> hiddenT[o][b]
// ---------------------------------------------------------------------------
__global__ __launch_bounds__(256) void fc1_reduce(
    const float* __restrict__ partial, const float* __restrict__ bias,
    float* __restrict__ hiddenT)
{
    int idx = blockIdx.x * 256 + threadIdx.x;   // o*64 + b
    int o = idx >> 6;
    float s = bias[o];
    #pragma unroll
    for (int i = 0; i < 32; ++i) s += partial[(size_t)i * 131072 + idx];
    hiddenT[idx] = fmaxf(s, 0.f);
}

// ---------------------------------------------------------------------------
// fc2: out[b][o] = sum_k hiddenT[k][b] * w2[o][k] + b2[o]
// wave = 8 outputs, lanes = b. 288 blocks x 4 waves = 1152 waves x 8 = 9216 o.
// ---------------------------------------------------------------------------
__global__ __launch_bounds__(256) void fc2_kernel(
    const float* __restrict__ hiddenT, const float* __restrict__ w,
    const float* __restrict__ bias, float* __restrict__ out)
{
    int lane = threadIdx.x & 63;
    int wv   = __builtin_amdgcn_readfirstlane(threadIdx.x >> 6);
    int wid  = blockIdx.x * 4 + wv;
    size_t o0 = (size_t)wid * 8;

    const float* wp = w + o0 * 2048;
    const float* hp = hiddenT + lane;
    float acc[8];
    #pragma unroll
    for (int i = 0; i < 8; ++i) acc[i] = 0.f;

    for (int k = 0; k < 2048; k += 4) {
        float h0 = hp[(k + 0) * 64], h1 = hp[(k + 1) * 64];
        float h2 = hp[(k + 2) * 64], h3 = hp[(k + 3) * 64];
        #pragma unroll
        for (int o = 0; o < 8; ++o) {
            const float* wr = wp + (size_t)o * 2048 + k;    // wave-uniform -> s_load
            acc[o] = fmaf(h0, wr[0], fmaf(h1, wr[1], fmaf(h2, wr[2], fmaf(h3, wr[3], acc[o]))));
        }
    }
    #pragma unroll
    for (int o = 0; o < 8; ++o)
        out[(size_t)lane * 9216 + o0 + o] = acc[o] + bias[o0 + o];
}

// ---------------------------------------------------------------------------
extern "C" void kernel_launch(void* const* d_in, const int* in_sizes, int n_in,
                              void* d_out, int out_size, void* d_ws, size_t ws_size,
                              hipStream_t stream)
{
    const float* x       = (const float*)d_in[0];
    const float* wih0    = (const float*)d_in[1];
    const float* whh0    = (const float*)d_in[2];
    const float* bih0    = (const float*)d_in[3];
    const float* bhh0    = (const float*)d_in[4];
    const float* wih0r   = (const float*)d_in[5];
    const float* whh0r   = (const float*)d_in[6];
    const float* bih0r   = (const float*)d_in[7];
    const float* bhh0r   = (const float*)d_in[8];
    const float* wih1    = (const float*)d_in[9];
    const float* whh1    = (const float*)d_in[10];
    const float* bih1    = (const float*)d_in[11];
    const float* bhh1    = (const float*)d_in[12];
    const float* wih1r   = (const float*)d_in[13];
    const float* whh1r   = (const float*)d_in[14];
    const float* bih1r   = (const float*)d_in[15];
    const float* bhh1r   = (const float*)d_in[16];
    const float* fc1_w   = (const float*)d_in[17];
    const float* fc1_b   = (const float*)d_in[18];
    const float* fc2_w   = (const float*)d_in[19];
    const float* fc2_b   = (const float*)d_in[20];
    float* out = (float*)d_out;

    // workspace layout (floats)
    float* ws = (float*)d_ws;
    float* xpbuf   = ws;                        // 2*64*1024*128 = 16,777,216 f (67.1 MB); later reused as flatT (4,194,304 f)
    float* hbuf    = ws + 16777216;             // 64*1024*64    =  4,194,304 f (16.8 MB); h0 then h1
    float* partial = ws + 16777216 + 4194304;   // 32*2048*64    =  4,194,304 f (16.8 MB)
    float* hiddenT = partial + 4194304;         // 2048*64       =    131,072 f (0.5 MB)
    float* flatT   = xpbuf;

    // layer 0
    xp_kernel<9><<<65536, 256, 0, stream>>>(x, wih0, bih0, bhh0, wih0r, bih0r, bhh0r, xpbuf);
    lstm_rec<<<128, 64, 0, stream>>>(xpbuf, whh0, whh0r, hbuf);
    // layer 1
    xp_kernel<64><<<65536, 256, 0, stream>>>(hbuf, wih1, bih1, bhh1, wih1r, bih1r, bhh1r, xpbuf);
    lstm_rec<<<128, 64, 0, stream>>>(xpbuf, whh1, whh1r, hbuf);
    // head
    transpose64<<<1024, 256, 0, stream>>>(hbuf, flatT);
    fc1_partial<<<512, 256, 0, stream>>>(flatT, fc1_w, partial);
    fc1_reduce<<<512, 256, 0, stream>>>(partial, fc1_b, hiddenT);
    fc2_kernel<<<288, 256, 0, stream>>>(hiddenT, fc2_w, fc2_b, out);
}

// Round 6
// 3749.214 us; speedup vs baseline: 3.3036x; 3.3036x over previous
//
#include <hip/hip_runtime.h>

#define TT 1024
#define BB 64
#define HH 32
#define G4 128   // 4*H

__device__ __forceinline__ float rl(float v, int lane) {
    return __int_as_float(__builtin_amdgcn_readlane(__float_as_int(v), lane));
}
__device__ __forceinline__ float fexp2(float x) { return __builtin_amdgcn_exp2f(x); }
__device__ __forceinline__ float frcp(float x)  { return __builtin_amdgcn_rcpf(x); }

// ---------------------------------------------------------------------------
// xp = x @ w_ih.T + b_ih + b_hh  for both directions.
// out layout: xp[dir][b][t][128]
// ---------------------------------------------------------------------------
template <int D>
__global__ __launch_bounds__(256) void xp_kernel(
    const float* __restrict__ xin,
    const float* __restrict__ wih_f, const float* __restrict__ bih_f, const float* __restrict__ bhh_f,
    const float* __restrict__ wih_r, const float* __restrict__ bih_r, const float* __restrict__ bhh_r,
    float* __restrict__ xp)
{
    int bid   = blockIdx.x;
    int tpair = bid & (TT / 2 - 1); bid >>= 9;
    int b     = bid & (BB - 1);     bid >>= 6;
    int dir   = bid;
    int g     = threadIdx.x & 127;
    int t     = tpair * 2 + (threadIdx.x >> 7);

    const float* wih  = dir ? wih_r : wih_f;
    float bias        = dir ? (bih_r[g] + bhh_r[g]) : (bih_f[g] + bhh_f[g]);
    const float* xrow = xin + ((size_t)b * TT + t) * D;
    const float* wrow = wih + (size_t)g * D;

    float acc = bias;
    if constexpr ((D & 3) == 0) {
        #pragma unroll
        for (int d = 0; d < D; d += 4) {
            float4 xv = *(const float4*)(xrow + d);
            float4 wv = *(const float4*)(wrow + d);
            acc = fmaf(xv.x, wv.x, acc);
            acc = fmaf(xv.y, wv.y, acc);
            acc = fmaf(xv.z, wv.z, acc);
            acc = fmaf(xv.w, wv.w, acc);
        }
    } else {
        #pragma unroll
        for (int d = 0; d < D; ++d) acc = fmaf(xrow[d], wrow[d], acc);
    }
    xp[(((size_t)dir * BB + b) * TT + t) * G4 + g] = acc;
}

// ---------------------------------------------------------------------------
// LSTM recurrence, one wave per (dir, b). Lane l owns gate rows l and l+64.
// h broadcast via v_readlane; f/o cross half-wave via shfl_xor 32.
// (validated in round 1: absmax 9.8e-4 with this exact kernel)
// ---------------------------------------------------------------------------
__global__ __launch_bounds__(64) void lstm_rec(
    const float* __restrict__ xp,
    const float* __restrict__ whh_f,
    const float* __restrict__ whh_r,
    float* __restrict__ hout)
{
    const int l   = threadIdx.x;
    const int dir = blockIdx.x >> 6;
    const int b   = blockIdx.x & 63;
    const float* whh = dir ? whh_r : whh_f;

    float w0[32], w1[32];
    #pragma unroll
    for (int j = 0; j < 8; ++j) {
        float4 v0 = ((const float4*)whh)[l * 8 + j];
        w0[4*j+0] = v0.x; w0[4*j+1] = v0.y; w0[4*j+2] = v0.z; w0[4*j+3] = v0.w;
        float4 v1 = ((const float4*)whh)[(l + 64) * 8 + j];
        w1[4*j+0] = v1.x; w1[4*j+1] = v1.y; w1[4*j+2] = v1.z; w1[4*j+3] = v1.w;
    }

    const int t0 = dir ? (TT - 1) : 0;
    const ptrdiff_t xstep = dir ? -G4 : G4;
    const ptrdiff_t hstep = dir ? -64 : 64;
    const float* xptr = xp + (((size_t)dir * BB + b) * TT + t0) * G4;
    float* hptr = hout + ((size_t)b * TT + t0) * 64 + (dir ? HH : 0);

    const float LOG2E = 1.4426950408889634f;
    const float kmul = (l < HH) ? (-2.0f * LOG2E) : (-LOG2E);
    const float vA   = (l < HH) ? 2.0f : 1.0f;
    const float vB   = (l < HH) ? -1.0f : 0.0f;

    float c = 0.f, hval = 0.f;
    float pre0 = xptr[l], pre1 = xptr[l + 64];

    for (int s = 0; s < TT; ++s) {
        const float* xnext = xptr + xstep;   // prefetch always lands inside xp buffer
        float q00 = pre0, q01 = 0.f, q02 = 0.f, q03 = 0.f;
        float q10 = pre1, q11 = 0.f, q12 = 0.f, q13 = 0.f;
        pre0 = xnext[l]; pre1 = xnext[l + 64];

        #pragma unroll
        for (int j = 0; j < 32; j += 4) {
            float h0 = rl(hval, j + 0), h1 = rl(hval, j + 1);
            float h2 = rl(hval, j + 2), h3 = rl(hval, j + 3);
            q00 = fmaf(h0, w0[j+0], q00); q10 = fmaf(h0, w1[j+0], q10);
            q01 = fmaf(h1, w0[j+1], q01); q11 = fmaf(h1, w1[j+1], q11);
            q02 = fmaf(h2, w0[j+2], q02); q12 = fmaf(h2, w1[j+2], q12);
            q03 = fmaf(h3, w0[j+3], q03); q13 = fmaf(h3, w1[j+3], q13);
        }
        float g0 = (q00 + q01) + (q02 + q03);
        float g1 = (q10 + q11) + (q12 + q13);

        float s0 = frcp(1.0f + fexp2(-LOG2E * g0));
        float s1 = frcp(1.0f + fexp2(kmul * g1));
        float v1 = fmaf(s1, vA, vB);

        float ff = __shfl_xor(s0, 32);
        float oo = __shfl_xor(s1, 32);

        c = fmaf(ff, c, s0 * v1);
        float th = fmaf(frcp(1.0f + fexp2(-2.0f * LOG2E * c)), 2.0f, -1.0f);
        hval = oo * th;

        if (l < HH) hptr[l] = hval;
        hptr += hstep;
        xptr = xnext;
    }
}

// ---------------------------------------------------------------------------
// transpose h1 [64][65536] -> flatT [65536][64]
// ---------------------------------------------------------------------------
__global__ __launch_bounds__(256) void transpose64(
    const float* __restrict__ in, float* __restrict__ out)
{
    __shared__ float tile[64][65];
    int k0 = blockIdx.x * 64;
    int cc = threadIdx.x & 63;
    int r0 = threadIdx.x >> 6;
    #pragma unroll
    for (int i = 0; i < 16; ++i) {
        int b = r0 + i * 4;
        tile[b][cc] = in[(size_t)b * 65536 + k0 + cc];
    }
    __syncthreads();
    #pragma unroll
    for (int i = 0; i < 16; ++i) {
        int kr = r0 + i * 4;
        out[(size_t)(k0 + kr) * 64 + cc] = tile[cc][kr];
    }
}

// ---------------------------------------------------------------------------
// Skinny GEMM: partial[s][o][b] = sum_{k in s-range} W[o][k] * A[k][b]
// W [M][K] row-major streamed per-lane from global (read exactly once).
// A [K][64] staged in LDS per 128-k chunk (reg-prefetched, T14 style).
// Lane grid: 8 k-lanes (kl) x 8 b-octs (so). Thread tile: 8 o x 8 b.
// LDS layout: 16B slot (r, s) stored at phys slot r*16 + (s ^ ((r>>2)&7)).
//   Read (row = kq*32+4*kl+j): (r>>2)&7 == kl, so phys class (2*so)^kl mod 8
//   is hit by exactly 8 lanes -> 2 lanes/bank = conflict-free floor.
//   Write (row-group per 16 lanes): s ^ const permutation -> conflict-free.
// Per kq (32 k): 256 lane-FMA (512 VALU-cyc) vs 8 ds_read_b128 -> VALU-bound.
// Cross-k-lane shfl reduce at end; kl==0 stores.
// Grid: s-major-consecutive so same-s blocks share the A chunk in L2.
// ---------------------------------------------------------------------------
template <int M, int K, int S>
__global__ __launch_bounds__(256, 3) void gemm_skinny(
    const float* __restrict__ W, const float* __restrict__ A,
    float* __restrict__ partial)
{
    constexpr int KR = K / S;        // k-range per block
    constexpr int NSTG = KR / 128;   // LDS stages
    constexpr int OBN = M / 32;
    __shared__ float Alds[128 * 64];
    float4* Alds4 = (float4*)Alds;   // 2048 16B slots

    const int ob = blockIdx.x % OBN;
    const int s  = blockIdx.x / OBN;
    const int t  = threadIdx.x;
    const int wv = t >> 6;
    const int lane = t & 63;
    const int kl = lane & 7;
    const int so = lane >> 3;        // b-oct index; b0 = 8*so
    const int obase = ob * 32 + wv * 8;
    const size_t kbase = (size_t)s * KR;

    float acc[8][8];
    #pragma unroll
    for (int o = 0; o < 8; ++o)
        #pragma unroll
        for (int b = 0; b < 8; ++b) acc[o][b] = 0.f;

    const float* wbase = W + (size_t)obase * K + kbase + 4 * kl;
    const float4* asrc = (const float4*)(A + kbase * 64);

    // prefetch stage 0 to regs
    float4 vst[8];
    #pragma unroll
    for (int i = 0; i < 8; ++i) vst[i] = asrc[t + 256 * i];

    for (int st = 0; st < NSTG; ++st) {
        __syncthreads();                       // all waves done reading prev stage
        #pragma unroll
        for (int i = 0; i < 8; ++i) {
            int g = t + 256 * i;               // 16B slot (r = g>>4, s = g&15)
            Alds4[(g & ~15) | ((g & 15) ^ ((g >> 6) & 7))] = vst[i];
        }
        __syncthreads();
        if (st + 1 < NSTG) {                   // prefetch next stage under compute
            const float4* nsrc = asrc + (size_t)(st + 1) * 2048;
            #pragma unroll
            for (int i = 0; i < 8; ++i) vst[i] = nsrc[t + 256 * i];
        }
        const float* wst = wbase + st * 128;
        #pragma unroll
        for (int kq = 0; kq < 4; ++kq) {
            float4 w[8];
            #pragma unroll
            for (int o = 0; o < 8; ++o)
                w[o] = *(const float4*)(wst + (size_t)o * K + kq * 32);
            #pragma unroll
            for (int j = 0; j < 4; ++j) {
                int R = kq * 32 + 4 * kl + j;
                float4 a0 = Alds4[R * 16 + ((2 * so)     ^ kl)];
                float4 a1 = Alds4[R * 16 + ((2 * so + 1) ^ kl)];
                #pragma unroll
                for (int o = 0; o < 8; ++o) {
                    float wj = ((const float*)&w[o])[j];
                    acc[o][0] = fmaf(wj, a0.x, acc[o][0]);
                    acc[o][1] = fmaf(wj, a0.y, acc[o][1]);
                    acc[o][2] = fmaf(wj, a0.z, acc[o][2]);
                    acc[o][3] = fmaf(wj, a0.w, acc[o][3]);
                    acc[o][4] = fmaf(wj, a1.x, acc[o][4]);
                    acc[o][5] = fmaf(wj, a1.y, acc[o][5]);
                    acc[o][6] = fmaf(wj, a1.z, acc[o][6]);
                    acc[o][7] = fmaf(wj, a1.w, acc[o][7]);
                }
            }
        }
    }

    #pragma unroll
    for (int o = 0; o < 8; ++o)
        #pragma unroll
        for (int b = 0; b < 8; ++b) {
            float v = acc[o][b];
            v += __shfl_xor(v, 1);
            v += __shfl_xor(v, 2);
            v += __shfl_xor(v, 4);
            acc[o][b] = v;
        }
    if (kl == 0) {
        float* pp = partial + ((size_t)s * M + obase) * 64 + 8 * so;
        #pragma unroll
        for (int o = 0; o < 8; ++o) {
            *(float4*)&pp[(size_t)o * 64]     = make_float4(acc[o][0], acc[o][1], acc[o][2], acc[o][3]);
            *(float4*)&pp[(size_t)o * 64 + 4] = make_float4(acc[o][4], acc[o][5], acc[o][6], acc[o][7]);
        }
    }
}

// ---------------------------------------------------------------------------
// reduce fc1 partials (S=16) + bias + relu -> hiddenT[o][b]
// ---------------------------------------------------------------------------
__global__ __launch_bounds__(256) void fc1_reduce(
    const float* __restrict__ partial, const float* __restrict__ bias,
    float* __restrict__ hiddenT)
{
    int idx = blockIdx.x * 256 + threadIdx.x;   // o*64 + b
    int o = idx >> 6;
    float s = bias[o];
    #pragma unroll
    for (int i = 0; i < 16; ++i) s += partial[(size_t)i * 131072 + idx];
    hiddenT[idx] = fmaxf(s, 0.f);
}

// ---------------------------------------------------------------------------
// reduce fc2 partials (S=4) + bias, transpose to out[b][o]
// ---------------------------------------------------------------------------
__global__ __launch_bounds__(256) void fc2_reduce(
    const float* __restrict__ partial, const float* __restrict__ bias,
    float* __restrict__ out)
{
    __shared__ float tile[64][65];
    int o0 = blockIdx.x * 64;
    int t = threadIdx.x;
    #pragma unroll
    for (int i = 0; i < 16; ++i) {
        int id = t + 256 * i;
        int ol = id >> 6, b = id & 63;
        float v = bias[o0 + ol];
        #pragma unroll
        for (int s = 0; s < 4; ++s)
            v += partial[((size_t)s * 9216 + o0 + ol) * 64 + b];
        tile[ol][b] = v;
    }
    __syncthreads();
    #pragma unroll
    for (int i = 0; i < 16; ++i) {
        int id = t + 256 * i;
        int b = id >> 6, ol = id & 63;
        out[(size_t)b * 9216 + o0 + ol] = tile[ol][b];
    }
}

// ---------------------------------------------------------------------------
extern "C" void kernel_launch(void* const* d_in, const int* in_sizes, int n_in,
                              void* d_out, int out_size, void* d_ws, size_t ws_size,
                              hipStream_t stream)
{
    const float* x       = (const float*)d_in[0];
    const float* wih0    = (const float*)d_in[1];
    const float* whh0    = (const float*)d_in[2];
    const float* bih0    = (const float*)d_in[3];
    const float* bhh0    = (const float*)d_in[4];
    const float* wih0r   = (const float*)d_in[5];
    const float* whh0r   = (const float*)d_in[6];
    const float* bih0r   = (const float*)d_in[7];
    const float* bhh0r   = (const float*)d_in[8];
    const float* wih1    = (const float*)d_in[9];
    const float* whh1    = (const float*)d_in[10];
    const float* bih1    = (const float*)d_in[11];
    const float* bhh1    = (const float*)d_in[12];
    const float* wih1r   = (const float*)d_in[13];
    const float* whh1r   = (const float*)d_in[14];
    const float* bih1r   = (const float*)d_in[15];
    const float* bhh1r   = (const float*)d_in[16];
    const float* fc1_w   = (const float*)d_in[17];
    const float* fc1_b   = (const float*)d_in[18];
    const float* fc2_w   = (const float*)d_in[19];
    const float* fc2_b   = (const float*)d_in[20];
    float* out = (float*)d_out;

    // workspace layout (floats): total 23,461,888 f = 93.9 MB
    float* ws = (float*)d_ws;
    float* xpbuf   = ws;                        // 16,777,216 f; reused as flatT
    float* hbuf    = ws + 16777216;             //  4,194,304 f
    float* partial = hbuf + 4194304;            //  2,359,296 f (max of fc1/fc2 partials)
    float* hiddenT = partial + 2359296;         //    131,072 f
    float* flatT   = xpbuf;

    // layer 0
    xp_kernel<9><<<65536, 256, 0, stream>>>(x, wih0, bih0, bhh0, wih0r, bih0r, bhh0r, xpbuf);
    lstm_rec<<<128, 64, 0, stream>>>(xpbuf, whh0, whh0r, hbuf);
    // layer 1
    xp_kernel<64><<<65536, 256, 0, stream>>>(hbuf, wih1, bih1, bhh1, wih1r, bih1r, bhh1r, xpbuf);
    lstm_rec<<<128, 64, 0, stream>>>(xpbuf, whh1, whh1r, hbuf);
    // head
    transpose64<<<1024, 256, 0, stream>>>(hbuf, flatT);
    gemm_skinny<2048, 65536, 16><<<1024, 256, 0, stream>>>(fc1_w, flatT, partial);
    fc1_reduce<<<512, 256, 0, stream>>>(partial, fc1_b, hiddenT);
    gemm_skinny<9216, 2048, 4><<<1152, 256, 0, stream>>>(fc2_w, hiddenT, partial);
    fc2_reduce<<<144, 256, 0, stream>>>(partial, fc2_b, out);
}